// Round 15
// baseline (318.671 us; speedup 1.0000x reference)
//
#include <hip/hip_runtime.h>
#include <hip/hip_bf16.h>
#include <math.h>

// Problem constants (from reference setup_inputs)
constexpr int B  = 4;
constexpr int N  = 2048;
constexpr int D  = 128;
constexpr int De = 8;
constexpr int KS = 8;              // split-K factor for agg
constexpr float LN_EPS = 1e-5f;

typedef __bf16 bf16x8 __attribute__((ext_vector_type(8)));
typedef float  f32x4v __attribute__((ext_vector_type(4)));

__device__ inline ushort f2bf(float f) {
    uint u = __float_as_uint(f);
    return (ushort)((u + 0x7fffu + ((u >> 16) & 1u)) >> 16);   // RNE
}

// ---------------------------------------------------------------------------
// Kernel 1: hT16[b][d][n] = bf16(h[b][n][d])  -- transposed cast (2MB out).
// ---------------------------------------------------------------------------
__global__ __launch_bounds__(256) void k_hcast(const float* __restrict__ h,
                                               ushort* __restrict__ hT16) {
    __shared__ float tile[32][33];
    int b  = blockIdx.z;
    int n0 = blockIdx.x * 32, d0 = blockIdx.y * 32;
    int t  = threadIdx.x;
    int r = t >> 3, c = (t & 7) * 4;
    float4 v = *reinterpret_cast<const float4*>(h + ((long long)b * N + n0 + r) * D + d0 + c);
    tile[r][c] = v.x; tile[r][c + 1] = v.y; tile[r][c + 2] = v.z; tile[r][c + 3] = v.w;
    __syncthreads();
    ushort4 o;
    o.x = f2bf(tile[c + 0][r]);
    o.y = f2bf(tile[c + 1][r]);
    o.z = f2bf(tile[c + 2][r]);
    o.w = f2bf(tile[c + 3][r]);
    *reinterpret_cast<ushort4*>(hT16 + ((long long)b * D + d0 + r) * N + n0 + c) = o;
}

// ---------------------------------------------------------------------------
// Kernel 2: e-stream, ITEM-PER-LANE (shfl-free A/B vs round 9/14).
//   out_e = e (copy); w16 = bf16(exp(||e||)).
// Lane t owns f4 pair (2t, 2t+1) = one full 8-float item -> zero cross-lane
// traffic (was 8 ds_swizzle round-trips/thread), w16 store dense 2B/lane.
// Per-instruction addresses are 32B-lane-strided (half-covered lines); the
// back-to-back pair covers lines fully, L2 merges.
// Max-subtraction skipped: ||e|| <= ~8.5 (chi2(8)) -> exp <= 5e3, fp32-safe.
// ---------------------------------------------------------------------------
__global__ __launch_bounds__(256) void k_escore(const float* __restrict__ e,
                                                float* __restrict__ out_e,
                                                ushort* __restrict__ w16) {
    const f32x4v* src = reinterpret_cast<const f32x4v*>(e);
    f32x4v*       dst = reinterpret_cast<f32x4v*>(out_e);
    long long base = (long long)blockIdx.x * 2048;   // f4 units (32KB/block)
    int t = threadIdx.x;

    #pragma unroll
    for (int p = 0; p < 4; ++p) {
        long long i4 = base + p * 512 + 2 * t;
        f32x4v v0 = __builtin_nontemporal_load(&src[i4]);
        f32x4v v1 = __builtin_nontemporal_load(&src[i4 + 1]);
        dst[i4]     = v0;
        dst[i4 + 1] = v1;
        float ss = v0.x * v0.x + v0.y * v0.y + v0.z * v0.z + v0.w * v0.w
                 + v1.x * v1.x + v1.y * v1.y + v1.z * v1.z + v1.w * v1.w;
        float val = __expf(sqrtf(ss));
        w16[i4 >> 1] = f2bf(val);    // item idx = base/2 + p*256 + t (dense/wave)
    }
}

// ---------------------------------------------------------------------------
// Kernel 3: deterministic per-row sum of w16 -> inv_rowsum = 1/sum.
// ---------------------------------------------------------------------------
__global__ __launch_bounds__(256) void k_rowsum(const ushort* __restrict__ w16,
                                                float* __restrict__ inv_rowsum) {
    __shared__ float red[4];
    long long row = blockIdx.x;
    int t = threadIdx.x;
    uint4 v = *reinterpret_cast<const uint4*>(w16 + row * (long long)N + t * 8);
    uint u[4] = {v.x, v.y, v.z, v.w};
    float s = 0.0f;
    #pragma unroll
    for (int q = 0; q < 4; ++q) {
        s += __uint_as_float(u[q] << 16);
        s += __uint_as_float(u[q] & 0xffff0000u);
    }
    #pragma unroll
    for (int off = 32; off > 0; off >>= 1) s += __shfl_xor(s, off);
    if ((t & 63) == 0) red[t >> 6] = s;
    __syncthreads();
    if (t == 0)
        inv_rowsum[row] = 1.0f / (red[0] + red[1] + red[2] + red[3]);
}

// ---------------------------------------------------------------------------
// Kernel 4: MFMA split-K agg, BK=64, register prefetch (round-9 verified).
//  aggp[z][b,i,:] = sum_{j in slice} w_ij * h_j
// A = w16 [BM=64][64] bf16, B = hT16 [D=128][64] bf16, pitch 72 ushorts.
// 256 thr = 4 waves (2x2), wave-tile 32x64, 16 MFMA/wave per K-step.
// grid (N/64, B, KS) = 1024 blocks.
// ---------------------------------------------------------------------------
__global__ __launch_bounds__(256, 3) void k_agg(const ushort* __restrict__ w16,
                                                const ushort* __restrict__ hT16,
                                                float* __restrict__ aggp) {
    constexpr int BM = 64;
    constexpr int BK = 64;
    constexpr int KC = N / KS;            // 256
    __shared__ ushort A_s[BM][72];        // w rows
    __shared__ ushort B_s[D][72];         // h cols (hT rows)

    int b  = blockIdx.y;
    int i0 = blockIdx.x * BM;
    int kbase = blockIdx.z * KC;
    int t  = threadIdx.x;
    int wid = t >> 6, lane = t & 63;
    int wr = wid >> 1, wc = wid & 1;      // wave tile: rows wr*32.., cols wc*64..
    int lr = lane & 15, lk = (lane >> 4) * 8;

    const ushort* wb = w16 + ((long long)b * N + i0) * N + kbase;
    const ushort* hb = hT16 + (long long)b * D * N + kbase;

    f32x4v acc[2][4] = {};

    int ar = t >> 2, ac = (t & 3) * 8;    // A: row ar, 2 quads at ac, ac+32
    int brr = t >> 1, bc = (t & 1) * 32;  // B: row brr, 4 quads at bc+{0,8,16,24}

    // prologue: load tile 0
    uint4 av0 = *reinterpret_cast<const uint4*>(wb + (long long)ar * N + ac);
    uint4 av1 = *reinterpret_cast<const uint4*>(wb + (long long)ar * N + ac + 32);
    uint4 bv0 = *reinterpret_cast<const uint4*>(hb + (long long)brr * N + bc);
    uint4 bv1 = *reinterpret_cast<const uint4*>(hb + (long long)brr * N + bc + 8);
    uint4 bv2 = *reinterpret_cast<const uint4*>(hb + (long long)brr * N + bc + 16);
    uint4 bv3 = *reinterpret_cast<const uint4*>(hb + (long long)brr * N + bc + 24);

    for (int k0 = 0; k0 < KC; k0 += BK) {
        __syncthreads();   // previous iteration's frag reads done
        *reinterpret_cast<uint4*>(&A_s[ar][ac])      = av0;
        *reinterpret_cast<uint4*>(&A_s[ar][ac + 32]) = av1;
        *reinterpret_cast<uint4*>(&B_s[brr][bc])      = bv0;
        *reinterpret_cast<uint4*>(&B_s[brr][bc + 8])  = bv1;
        *reinterpret_cast<uint4*>(&B_s[brr][bc + 16]) = bv2;
        *reinterpret_cast<uint4*>(&B_s[brr][bc + 24]) = bv3;
        __syncthreads();   // tile ready

        int kn = k0 + BK;
        if (kn < KC) {     // prefetch next tile; latency hides under MFMAs
            av0 = *reinterpret_cast<const uint4*>(wb + (long long)ar * N + kn + ac);
            av1 = *reinterpret_cast<const uint4*>(wb + (long long)ar * N + kn + ac + 32);
            bv0 = *reinterpret_cast<const uint4*>(hb + (long long)brr * N + kn + bc);
            bv1 = *reinterpret_cast<const uint4*>(hb + (long long)brr * N + kn + bc + 8);
            bv2 = *reinterpret_cast<const uint4*>(hb + (long long)brr * N + kn + bc + 16);
            bv3 = *reinterpret_cast<const uint4*>(hb + (long long)brr * N + kn + bc + 24);
        }

        #pragma unroll
        for (int s = 0; s < 2; ++s) {
            int ko = s * 32 + lk;
            bf16x8 af[2], bfr[4];
            #pragma unroll
            for (int fm = 0; fm < 2; ++fm)
                af[fm] = *reinterpret_cast<const bf16x8*>(&A_s[wr * 32 + fm * 16 + lr][ko]);
            #pragma unroll
            for (int fn = 0; fn < 4; ++fn)
                bfr[fn] = *reinterpret_cast<const bf16x8*>(&B_s[wc * 64 + fn * 16 + lr][ko]);
            #pragma unroll
            for (int fm = 0; fm < 2; ++fm)
                #pragma unroll
                for (int fn = 0; fn < 4; ++fn)
                    acc[fm][fn] = __builtin_amdgcn_mfma_f32_16x16x32_bf16(
                        af[fm], bfr[fn], acc[fm][fn], 0, 0, 0);
        }
    }

    // D frag: row m = (lane>>4)*4 + r, col n = lane&15  [m89-verified layout]
    float* ap = aggp + (long long)blockIdx.z * B * N * D + ((long long)b * N + i0) * D;
    #pragma unroll
    for (int fm = 0; fm < 2; ++fm)
        #pragma unroll
        for (int fn = 0; fn < 4; ++fn)
            #pragma unroll
            for (int r = 0; r < 4; ++r) {
                int row = wr * 32 + fm * 16 + (lane >> 4) * 4 + r;
                int col = wc * 64 + fn * 16 + lr;
                ap[(long long)row * D + col] = acc[fm][fn][r];
            }
}

// ---------------------------------------------------------------------------
// Kernel 5: per row: x = h + inv_rowsum * sum_s aggp[s];
//           z = x @ W^T + b; LN; ReLU; + h.
// ---------------------------------------------------------------------------
__global__ __launch_bounds__(128) void k_out(const float* __restrict__ h,
                                             const float* __restrict__ aggp,
                                             const float* __restrict__ inv_rowsum,
                                             const float* __restrict__ Ww,
                                             const float* __restrict__ Wb,
                                             const float* __restrict__ ln_g,
                                             const float* __restrict__ ln_b,
                                             float* __restrict__ out) {
    __shared__ __align__(16) float x_s[D];
    __shared__ float red[4];
    constexpr long long BND = (long long)B * N * D;

    long long row = blockIdx.x;    // b*N + i
    int d = threadIdx.x;

    float hv = h[row * D + d];
    float a = 0.0f;
    #pragma unroll
    for (int s = 0; s < KS; ++s)
        a += aggp[s * BND + row * D + d];
    a *= inv_rowsum[row];
    x_s[d] = hv + a;
    __syncthreads();

    const float4* wrow = reinterpret_cast<const float4*>(Ww + (long long)d * D);
    const float4* xv   = reinterpret_cast<const float4*>(x_s);
    float z = 0.0f;
    #pragma unroll
    for (int k = 0; k < D / 4; ++k) {
        float4 wv = wrow[k];
        float4 vv = xv[k];
        z += wv.x * vv.x + wv.y * vv.y + wv.z * vv.z + wv.w * vv.w;
    }
    z += Wb[d];

    float s = z;
    #pragma unroll
    for (int off = 32; off > 0; off >>= 1) s += __shfl_xor(s, off);
    if ((d & 63) == 0) red[d >> 6] = s;
    __syncthreads();
    float mu = (red[0] + red[1]) * (1.0f / (float)D);
    __syncthreads();

    float dev = z - mu;
    float s2 = dev * dev;
    #pragma unroll
    for (int off = 32; off > 0; off >>= 1) s2 += __shfl_xor(s2, off);
    if ((d & 63) == 0) red[d >> 6] = s2;
    __syncthreads();
    float var = (red[0] + red[1]) * (1.0f / (float)D);

    float y = dev * rsqrtf(var + LN_EPS) * ln_g[d] + ln_b[d];
    out[row * D + d] = fmaxf(y, 0.0f) + hv;
}

// ---------------------------------------------------------------------------
extern "C" void kernel_launch(void* const* d_in, const int* in_sizes, int n_in,
                              void* d_out, int out_size, void* d_ws, size_t ws_size,
                              hipStream_t stream) {
    const float* h    = (const float*)d_in[0];   // [B,N,D]
    const float* e    = (const float*)d_in[1];   // [B,N,N,De]
    const float* Ww   = (const float*)d_in[2];   // [D,D]
    const float* Wb   = (const float*)d_in[3];   // [D]
    const float* ln_g = (const float*)d_in[4];   // [D]
    const float* ln_b = (const float*)d_in[5];   // [D]

    float* out   = (float*)d_out;
    float* out_h = out;                                   // [B,N,D]
    float* out_e = out + (size_t)B * N * D;               // [B,N,N,De]

    ushort* w16  = (ushort*)d_ws;                         // [B,N,N] bf16   (33.5 MB)
    ushort* hT16 = w16 + (size_t)B * N * N;               // [B,D,N] bf16   (2.1 MB)
    float*  aggp = (float*)(hT16 + (size_t)B * D * N);    // [KS][B,N,D]    (33.5 MB)
    float*  inv_rowsum = aggp + (size_t)KS * B * N * D;   // [B*N]          (32 KB)

    dim3 gh(N / 32, D / 32, B);
    k_hcast<<<gh, 256, 0, stream>>>(h, hT16);

    long long total_f4 = (long long)B * N * N * De / 4;   // 33.55M float4
    int eblocks = (int)(total_f4 / 2048);                 // 16384 blocks (32KB each)
    k_escore<<<eblocks, 256, 0, stream>>>(e, out_e, w16);

    k_rowsum<<<B * N, 256, 0, stream>>>(w16, inv_rowsum);
    dim3 g2(N / 64, B, KS);
    k_agg<<<g2, 256, 0, stream>>>(w16, hT16, aggp);
    k_out<<<B * N, 128, 0, stream>>>(h, aggp, inv_rowsum, Ww, Wb, ln_g, ln_b, out_h);
}

// Round 16
// 288.273 us; speedup vs baseline: 1.1054x; 1.1054x over previous
//
#include <hip/hip_runtime.h>
#include <hip/hip_bf16.h>
#include <math.h>

// Problem constants (from reference setup_inputs)
constexpr int B  = 4;
constexpr int N  = 2048;
constexpr int D  = 128;
constexpr int De = 8;
constexpr int KS = 8;              // split-K factor for agg
constexpr float LN_EPS = 1e-5f;

typedef __bf16 bf16x8 __attribute__((ext_vector_type(8)));
typedef float  f32x4v __attribute__((ext_vector_type(4)));

__device__ inline ushort f2bf(float f) {
    uint u = __float_as_uint(f);
    return (ushort)((u + 0x7fffu + ((u >> 16) & 1u)) >> 16);   // RNE
}

// ---------------------------------------------------------------------------
// Kernel 1: hT16[b][d][n] = bf16(h[b][n][d])  -- transposed cast (2MB out).
// ---------------------------------------------------------------------------
__global__ __launch_bounds__(256) void k_hcast(const float* __restrict__ h,
                                               ushort* __restrict__ hT16) {
    __shared__ float tile[32][33];
    int b  = blockIdx.z;
    int n0 = blockIdx.x * 32, d0 = blockIdx.y * 32;
    int t  = threadIdx.x;
    int r = t >> 3, c = (t & 7) * 4;
    float4 v = *reinterpret_cast<const float4*>(h + ((long long)b * N + n0 + r) * D + d0 + c);
    tile[r][c] = v.x; tile[r][c + 1] = v.y; tile[r][c + 2] = v.z; tile[r][c + 3] = v.w;
    __syncthreads();
    ushort4 o;
    o.x = f2bf(tile[c + 0][r]);
    o.y = f2bf(tile[c + 1][r]);
    o.z = f2bf(tile[c + 2][r]);
    o.w = f2bf(tile[c + 3][r]);
    *reinterpret_cast<ushort4*>(hT16 + ((long long)b * D + d0 + r) * N + n0 + c) = o;
}

// ---------------------------------------------------------------------------
// Kernel 2: e-stream — ROUND-9 MEASURED-BEST FORM (289.5us total config).
//   out_e = e (copy); w16 = bf16(exp(||e||))  [unnormalized numerator]
// Lane-contiguous: lane covers f4 'base + p*256 + t' (16B/lane, 1KB/wave/op);
// nt LOADS (read-once); cached stores. Item = f4 pair on lane pair: norm via
// shfl_xor(1); bf16 pack via shfl_xor(2); lanes t%4==0 write one uint.
// Measured A/B history: interleaved-4+ntload 289.5 (r9) < ntstore 295.9 (r14)
// < ILP8+atomics 298.8 (r13) < item-per-lane 318.7 (r15). This is the optimum.
// Max-subtraction skipped: ||e|| <= ~8.5 (chi2(8)) -> exp <= 5e3, fp32-safe.
// ---------------------------------------------------------------------------
__global__ __launch_bounds__(256) void k_escore(const float* __restrict__ e,
                                                float* __restrict__ out_e,
                                                uint* __restrict__ w32) {
    const f32x4v* src = reinterpret_cast<const f32x4v*>(e);
    f32x4v*       dst = reinterpret_cast<f32x4v*>(out_e);
    long long base = (long long)blockIdx.x * 1024;   // f4 units (16KB/block)
    int t = threadIdx.x;

    #pragma unroll
    for (int p = 0; p < 4; ++p) {
        long long i4 = base + p * 256 + t;
        f32x4v v = __builtin_nontemporal_load(&src[i4]);
        dst[i4] = v;
        float ss = v.x * v.x + v.y * v.y + v.z * v.z + v.w * v.w;
        ss += __shfl_xor(ss, 1);                     // full ||item||^2 on lane pair
        float val = __expf(sqrtf(ss));
        uint bf = f2bf(val);
        uint partner = (uint)__shfl_xor((int)bf, 2); // neighbor item's bf16
        if ((t & 3) == 0)
            w32[i4 >> 2] = bf | (partner << 16);
    }
}

// ---------------------------------------------------------------------------
// Kernel 3: MFMA split-K agg + FUSED ROW-SUM via ones-vector MFMA.
//  aggp[z][b,i,:]  = sum_{j in slice} w_ij * h_j
//  partial[z][b,i] = sum_{j in slice} w_ij          (softmax denominator)
// The denominator comes free from the staged A-tile: 2 extra MFMAs/K-step
// with a constant all-ones B-fragment give D[m][*] = rowsum. This deletes
// the separate k_rowsum kernel (-34MB HBM re-read, -1 launch).
// A = w16 [BM=64][64] bf16, B = hT16 [D=128][64] bf16, pitch 72 ushorts.
// 256 thr = 4 waves (2x2), wave-tile 32x64, BK=64, register prefetch.
// grid (N/64, B, KS) = 1024 blocks.
// ---------------------------------------------------------------------------
__global__ __launch_bounds__(256, 3) void k_agg(const ushort* __restrict__ w16,
                                                const ushort* __restrict__ hT16,
                                                float* __restrict__ aggp,
                                                float* __restrict__ partial) {
    constexpr int BM = 64;
    constexpr int BK = 64;
    constexpr int KC = N / KS;            // 256
    __shared__ ushort A_s[BM][72];        // w rows
    __shared__ ushort B_s[D][72];         // h cols (hT rows)

    int b  = blockIdx.y;
    int i0 = blockIdx.x * BM;
    int kbase = blockIdx.z * KC;
    int t  = threadIdx.x;
    int wid = t >> 6, lane = t & 63;
    int wr = wid >> 1, wc = wid & 1;      // wave tile: rows wr*32.., cols wc*64..
    int lr = lane & 15, lk = (lane >> 4) * 8;

    const ushort* wb = w16 + ((long long)b * N + i0) * N + kbase;
    const ushort* hb = hT16 + (long long)b * D * N + kbase;

    f32x4v acc[2][4] = {};
    f32x4v acc_sum[2] = {};               // ones-MFMA row-sum accumulators

    // constant all-ones bf16 B-fragment (1.0bf16 = 0x3F80)
    ushort one_bits = 0x3F80;
    __bf16 one_bf = *reinterpret_cast<__bf16*>(&one_bits);
    bf16x8 ones = {one_bf, one_bf, one_bf, one_bf, one_bf, one_bf, one_bf, one_bf};

    int ar = t >> 2, ac = (t & 3) * 8;    // A: row ar, 2 quads at ac, ac+32
    int brr = t >> 1, bc = (t & 1) * 32;  // B: row brr, 4 quads at bc+{0,8,16,24}

    // prologue: load tile 0
    uint4 av0 = *reinterpret_cast<const uint4*>(wb + (long long)ar * N + ac);
    uint4 av1 = *reinterpret_cast<const uint4*>(wb + (long long)ar * N + ac + 32);
    uint4 bv0 = *reinterpret_cast<const uint4*>(hb + (long long)brr * N + bc);
    uint4 bv1 = *reinterpret_cast<const uint4*>(hb + (long long)brr * N + bc + 8);
    uint4 bv2 = *reinterpret_cast<const uint4*>(hb + (long long)brr * N + bc + 16);
    uint4 bv3 = *reinterpret_cast<const uint4*>(hb + (long long)brr * N + bc + 24);

    for (int k0 = 0; k0 < KC; k0 += BK) {
        __syncthreads();   // previous iteration's frag reads done
        *reinterpret_cast<uint4*>(&A_s[ar][ac])      = av0;
        *reinterpret_cast<uint4*>(&A_s[ar][ac + 32]) = av1;
        *reinterpret_cast<uint4*>(&B_s[brr][bc])      = bv0;
        *reinterpret_cast<uint4*>(&B_s[brr][bc + 8])  = bv1;
        *reinterpret_cast<uint4*>(&B_s[brr][bc + 16]) = bv2;
        *reinterpret_cast<uint4*>(&B_s[brr][bc + 24]) = bv3;
        __syncthreads();   // tile ready

        int kn = k0 + BK;
        if (kn < KC) {     // prefetch next tile; latency hides under MFMAs
            av0 = *reinterpret_cast<const uint4*>(wb + (long long)ar * N + kn + ac);
            av1 = *reinterpret_cast<const uint4*>(wb + (long long)ar * N + kn + ac + 32);
            bv0 = *reinterpret_cast<const uint4*>(hb + (long long)brr * N + kn + bc);
            bv1 = *reinterpret_cast<const uint4*>(hb + (long long)brr * N + kn + bc + 8);
            bv2 = *reinterpret_cast<const uint4*>(hb + (long long)brr * N + kn + bc + 16);
            bv3 = *reinterpret_cast<const uint4*>(hb + (long long)brr * N + kn + bc + 24);
        }

        #pragma unroll
        for (int s = 0; s < 2; ++s) {
            int ko = s * 32 + lk;
            bf16x8 af[2], bfr[4];
            #pragma unroll
            for (int fm = 0; fm < 2; ++fm)
                af[fm] = *reinterpret_cast<const bf16x8*>(&A_s[wr * 32 + fm * 16 + lr][ko]);
            #pragma unroll
            for (int fn = 0; fn < 4; ++fn)
                bfr[fn] = *reinterpret_cast<const bf16x8*>(&B_s[wc * 64 + fn * 16 + lr][ko]);
            #pragma unroll
            for (int fm = 0; fm < 2; ++fm) {
                #pragma unroll
                for (int fn = 0; fn < 4; ++fn)
                    acc[fm][fn] = __builtin_amdgcn_mfma_f32_16x16x32_bf16(
                        af[fm], bfr[fn], acc[fm][fn], 0, 0, 0);
                acc_sum[fm] = __builtin_amdgcn_mfma_f32_16x16x32_bf16(
                    af[fm], ones, acc_sum[fm], 0, 0, 0);
            }
        }
    }

    // row-sum partials: D[m][n] identical over n; lanes with lr==0 hold col 0.
    // wc==0 waves only (wc==1 computes duplicates). 4 lanes x 2 fm x 4 r = 32 rows/wave.
    if (wc == 0 && lr == 0) {
        float* pp = partial + (long long)blockIdx.z * (B * N) + (long long)b * N + i0;
        #pragma unroll
        for (int fm = 0; fm < 2; ++fm)
            #pragma unroll
            for (int r = 0; r < 4; ++r)
                pp[wr * 32 + fm * 16 + (lane >> 4) * 4 + r] = acc_sum[fm][r];
    }

    // D frag: row m = (lane>>4)*4 + r, col n = lane&15  [m89-verified layout]
    float* ap = aggp + (long long)blockIdx.z * B * N * D + ((long long)b * N + i0) * D;
    #pragma unroll
    for (int fm = 0; fm < 2; ++fm)
        #pragma unroll
        for (int fn = 0; fn < 4; ++fn)
            #pragma unroll
            for (int r = 0; r < 4; ++r) {
                int row = wr * 32 + fm * 16 + (lane >> 4) * 4 + r;
                int col = wc * 64 + fn * 16 + lr;
                ap[(long long)row * D + col] = acc[fm][fn][r];
            }
}

// ---------------------------------------------------------------------------
// Kernel 4: per row: psum = sum_s partial[s]; x = h + (1/psum) sum_s aggp[s];
//           z = x @ W^T + b; LN; ReLU; + h.
// ---------------------------------------------------------------------------
__global__ __launch_bounds__(128) void k_out(const float* __restrict__ h,
                                             const float* __restrict__ aggp,
                                             const float* __restrict__ partial,
                                             const float* __restrict__ Ww,
                                             const float* __restrict__ Wb,
                                             const float* __restrict__ ln_g,
                                             const float* __restrict__ ln_b,
                                             float* __restrict__ out) {
    __shared__ __align__(16) float x_s[D];
    __shared__ float red[4];
    constexpr long long BND = (long long)B * N * D;
    constexpr long long BN  = (long long)B * N;

    long long row = blockIdx.x;    // b*N + i
    int d = threadIdx.x;

    float hv = h[row * D + d];
    float a = 0.0f;
    #pragma unroll
    for (int s = 0; s < KS; ++s)
        a += aggp[s * BND + row * D + d];
    float psum = 0.0f;
    #pragma unroll
    for (int s = 0; s < KS; ++s)
        psum += partial[s * BN + row];
    a *= (1.0f / psum);
    x_s[d] = hv + a;
    __syncthreads();

    const float4* wrow = reinterpret_cast<const float4*>(Ww + (long long)d * D);
    const float4* xv   = reinterpret_cast<const float4*>(x_s);
    float z = 0.0f;
    #pragma unroll
    for (int k = 0; k < D / 4; ++k) {
        float4 wv = wrow[k];
        float4 vv = xv[k];
        z += wv.x * vv.x + wv.y * vv.y + wv.z * vv.z + wv.w * vv.w;
    }
    z += Wb[d];

    float s = z;
    #pragma unroll
    for (int off = 32; off > 0; off >>= 1) s += __shfl_xor(s, off);
    if ((d & 63) == 0) red[d >> 6] = s;
    __syncthreads();
    float mu = (red[0] + red[1]) * (1.0f / (float)D);
    __syncthreads();

    float dev = z - mu;
    float s2 = dev * dev;
    #pragma unroll
    for (int off = 32; off > 0; off >>= 1) s2 += __shfl_xor(s2, off);
    if ((d & 63) == 0) red[d >> 6] = s2;
    __syncthreads();
    float var = (red[0] + red[1]) * (1.0f / (float)D);

    float y = dev * rsqrtf(var + LN_EPS) * ln_g[d] + ln_b[d];
    out[row * D + d] = fmaxf(y, 0.0f) + hv;
}

// ---------------------------------------------------------------------------
extern "C" void kernel_launch(void* const* d_in, const int* in_sizes, int n_in,
                              void* d_out, int out_size, void* d_ws, size_t ws_size,
                              hipStream_t stream) {
    const float* h    = (const float*)d_in[0];   // [B,N,D]
    const float* e    = (const float*)d_in[1];   // [B,N,N,De]
    const float* Ww   = (const float*)d_in[2];   // [D,D]
    const float* Wb   = (const float*)d_in[3];   // [D]
    const float* ln_g = (const float*)d_in[4];   // [D]
    const float* ln_b = (const float*)d_in[5];   // [D]

    float* out   = (float*)d_out;
    float* out_h = out;                                   // [B,N,D]
    float* out_e = out + (size_t)B * N * D;               // [B,N,N,De]

    ushort* w16  = (ushort*)d_ws;                         // [B,N,N] bf16   (33.5 MB)
    ushort* hT16 = w16 + (size_t)B * N * N;               // [B,D,N] bf16   (2.1 MB)
    float*  aggp = (float*)(hT16 + (size_t)B * D * N);    // [KS][B,N,D]    (33.5 MB)
    float*  partial = aggp + (size_t)KS * B * N * D;      // [KS][B*N]      (256 KB)

    dim3 gh(N / 32, D / 32, B);
    k_hcast<<<gh, 256, 0, stream>>>(h, hT16);

    long long total_f4 = (long long)B * N * N * De / 4;   // 33.55M float4
    int eblocks = (int)(total_f4 / 1024);                 // 32768 blocks (16KB each)
    k_escore<<<eblocks, 256, 0, stream>>>(e, out_e, (uint*)w16);

    dim3 g2(N / 64, B, KS);
    k_agg<<<g2, 256, 0, stream>>>(w16, hT16, aggp, partial);
    k_out<<<B * N, 128, 0, stream>>>(h, aggp, partial, Ww, Wb, ln_g, ln_b, out_h);
}

// Round 17
// 285.984 us; speedup vs baseline: 1.1143x; 1.0080x over previous
//
#include <hip/hip_runtime.h>
#include <hip/hip_bf16.h>
#include <math.h>

// Problem constants (from reference setup_inputs)
constexpr int B  = 4;
constexpr int N  = 2048;
constexpr int D  = 128;
constexpr int De = 8;
constexpr int KS = 8;              // split-K factor for agg
constexpr float LN_EPS = 1e-5f;

typedef __bf16 bf16x8 __attribute__((ext_vector_type(8)));
typedef float  f32x4v __attribute__((ext_vector_type(4)));

__device__ inline ushort f2bf(float f) {
    uint u = __float_as_uint(f);
    return (ushort)((u + 0x7fffu + ((u >> 16) & 1u)) >> 16);   // RNE
}

// ---------------------------------------------------------------------------
// Kernel 1: hT16[b][d][n] = bf16(h[b][n][d])  -- transposed cast (2MB out).
// ---------------------------------------------------------------------------
__global__ __launch_bounds__(256) void k_hcast(const float* __restrict__ h,
                                               ushort* __restrict__ hT16) {
    __shared__ float tile[32][33];
    int b  = blockIdx.z;
    int n0 = blockIdx.x * 32, d0 = blockIdx.y * 32;
    int t  = threadIdx.x;
    int r = t >> 3, c = (t & 7) * 4;
    float4 v = *reinterpret_cast<const float4*>(h + ((long long)b * N + n0 + r) * D + d0 + c);
    tile[r][c] = v.x; tile[r][c + 1] = v.y; tile[r][c + 2] = v.z; tile[r][c + 3] = v.w;
    __syncthreads();
    ushort4 o;
    o.x = f2bf(tile[c + 0][r]);
    o.y = f2bf(tile[c + 1][r]);
    o.z = f2bf(tile[c + 2][r]);
    o.w = f2bf(tile[c + 3][r]);
    *reinterpret_cast<ushort4*>(hT16 + ((long long)b * D + d0 + r) * N + n0 + c) = o;
}

// ---------------------------------------------------------------------------
// Kernel 2: e-stream — ROUND-9 MEASURED-BEST FORM.
//   out_e = e (copy); w16 = bf16(exp(||e||))  [unnormalized numerator]
// Lane-contiguous (16B/lane, 1KB/wave/op); nt LOADS; cached stores; norm via
// shfl_xor(1); bf16 pack via shfl_xor(2); lanes t%4==0 write one uint.
// A/B history: this form 289.5 (r9) < ntstore 295.9 < ILP8+atomics 298.8 <
// item-per-lane 318.7. Max-subtraction skipped: ||e||<=~8.5 -> exp<=5e3.
// ---------------------------------------------------------------------------
__global__ __launch_bounds__(256) void k_escore(const float* __restrict__ e,
                                                float* __restrict__ out_e,
                                                uint* __restrict__ w32) {
    const f32x4v* src = reinterpret_cast<const f32x4v*>(e);
    f32x4v*       dst = reinterpret_cast<f32x4v*>(out_e);
    long long base = (long long)blockIdx.x * 1024;   // f4 units (16KB/block)
    int t = threadIdx.x;

    #pragma unroll
    for (int p = 0; p < 4; ++p) {
        long long i4 = base + p * 256 + t;
        f32x4v v = __builtin_nontemporal_load(&src[i4]);
        dst[i4] = v;
        float ss = v.x * v.x + v.y * v.y + v.z * v.z + v.w * v.w;
        ss += __shfl_xor(ss, 1);                     // full ||item||^2 on lane pair
        float val = __expf(sqrtf(ss));
        uint bf = f2bf(val);
        uint partner = (uint)__shfl_xor((int)bf, 2); // neighbor item's bf16
        if ((t & 3) == 0)
            w32[i4 >> 2] = bf | (partner << 16);
    }
}

// ---------------------------------------------------------------------------
// Kernel 3: MFMA split-K agg + fused row-sum (ones-vector MFMA).
//  aggp[z][b,i,:]  = sum_{j in slice} w_ij * h_j   -- stored BF16 (r17:
//    halves the 67MB fp32 round-trip; quantization error ~1e-4 after norm)
//  partial[z][b,i] = sum_{j in slice} w_ij          (fp32)
// A = w16 [BM=64][64] bf16, B = hT16 [D=128][64] bf16, pitch 72 ushorts.
// 256 thr = 4 waves (2x2), wave-tile 32x64, BK=64, register prefetch.
// grid (N/64, B, KS) = 1024 blocks.
// ---------------------------------------------------------------------------
__global__ __launch_bounds__(256, 3) void k_agg(const ushort* __restrict__ w16,
                                                const ushort* __restrict__ hT16,
                                                ushort* __restrict__ aggp,
                                                float* __restrict__ partial) {
    constexpr int BM = 64;
    constexpr int BK = 64;
    constexpr int KC = N / KS;            // 256
    __shared__ ushort A_s[BM][72];        // w rows
    __shared__ ushort B_s[D][72];         // h cols (hT rows)

    int b  = blockIdx.y;
    int i0 = blockIdx.x * BM;
    int kbase = blockIdx.z * KC;
    int t  = threadIdx.x;
    int wid = t >> 6, lane = t & 63;
    int wr = wid >> 1, wc = wid & 1;      // wave tile: rows wr*32.., cols wc*64..
    int lr = lane & 15, lk = (lane >> 4) * 8;

    const ushort* wb = w16 + ((long long)b * N + i0) * N + kbase;
    const ushort* hb = hT16 + (long long)b * D * N + kbase;

    f32x4v acc[2][4] = {};
    f32x4v acc_sum[2] = {};               // ones-MFMA row-sum accumulators

    ushort one_bits = 0x3F80;             // 1.0 bf16
    __bf16 one_bf = *reinterpret_cast<__bf16*>(&one_bits);
    bf16x8 ones = {one_bf, one_bf, one_bf, one_bf, one_bf, one_bf, one_bf, one_bf};

    int ar = t >> 2, ac = (t & 3) * 8;    // A: row ar, 2 quads at ac, ac+32
    int brr = t >> 1, bc = (t & 1) * 32;  // B: row brr, 4 quads at bc+{0,8,16,24}

    // prologue: load tile 0
    uint4 av0 = *reinterpret_cast<const uint4*>(wb + (long long)ar * N + ac);
    uint4 av1 = *reinterpret_cast<const uint4*>(wb + (long long)ar * N + ac + 32);
    uint4 bv0 = *reinterpret_cast<const uint4*>(hb + (long long)brr * N + bc);
    uint4 bv1 = *reinterpret_cast<const uint4*>(hb + (long long)brr * N + bc + 8);
    uint4 bv2 = *reinterpret_cast<const uint4*>(hb + (long long)brr * N + bc + 16);
    uint4 bv3 = *reinterpret_cast<const uint4*>(hb + (long long)brr * N + bc + 24);

    for (int k0 = 0; k0 < KC; k0 += BK) {
        __syncthreads();   // previous iteration's frag reads done
        *reinterpret_cast<uint4*>(&A_s[ar][ac])      = av0;
        *reinterpret_cast<uint4*>(&A_s[ar][ac + 32]) = av1;
        *reinterpret_cast<uint4*>(&B_s[brr][bc])      = bv0;
        *reinterpret_cast<uint4*>(&B_s[brr][bc + 8])  = bv1;
        *reinterpret_cast<uint4*>(&B_s[brr][bc + 16]) = bv2;
        *reinterpret_cast<uint4*>(&B_s[brr][bc + 24]) = bv3;
        __syncthreads();   // tile ready

        int kn = k0 + BK;
        if (kn < KC) {     // prefetch next tile; latency hides under MFMAs
            av0 = *reinterpret_cast<const uint4*>(wb + (long long)ar * N + kn + ac);
            av1 = *reinterpret_cast<const uint4*>(wb + (long long)ar * N + kn + ac + 32);
            bv0 = *reinterpret_cast<const uint4*>(hb + (long long)brr * N + kn + bc);
            bv1 = *reinterpret_cast<const uint4*>(hb + (long long)brr * N + kn + bc + 8);
            bv2 = *reinterpret_cast<const uint4*>(hb + (long long)brr * N + kn + bc + 16);
            bv3 = *reinterpret_cast<const uint4*>(hb + (long long)brr * N + kn + bc + 24);
        }

        #pragma unroll
        for (int s = 0; s < 2; ++s) {
            int ko = s * 32 + lk;
            bf16x8 af[2], bfr[4];
            #pragma unroll
            for (int fm = 0; fm < 2; ++fm)
                af[fm] = *reinterpret_cast<const bf16x8*>(&A_s[wr * 32 + fm * 16 + lr][ko]);
            #pragma unroll
            for (int fn = 0; fn < 4; ++fn)
                bfr[fn] = *reinterpret_cast<const bf16x8*>(&B_s[wc * 64 + fn * 16 + lr][ko]);
            #pragma unroll
            for (int fm = 0; fm < 2; ++fm) {
                #pragma unroll
                for (int fn = 0; fn < 4; ++fn)
                    acc[fm][fn] = __builtin_amdgcn_mfma_f32_16x16x32_bf16(
                        af[fm], bfr[fn], acc[fm][fn], 0, 0, 0);
                acc_sum[fm] = __builtin_amdgcn_mfma_f32_16x16x32_bf16(
                    af[fm], ones, acc_sum[fm], 0, 0, 0);
            }
        }
    }

    // row-sum partials: col 0 of the sum fragment; wc==0 waves, lr==0 lanes.
    if (wc == 0 && lr == 0) {
        float* pp = partial + (long long)blockIdx.z * (B * N) + (long long)b * N + i0;
        #pragma unroll
        for (int fm = 0; fm < 2; ++fm)
            #pragma unroll
            for (int r = 0; r < 4; ++r)
                pp[wr * 32 + fm * 16 + (lane >> 4) * 4 + r] = acc_sum[fm][r];
    }

    // D frag: row m = (lane>>4)*4 + r, col n = lane&15  [m89-verified layout]
    ushort* ap = aggp + (long long)blockIdx.z * B * N * D + ((long long)b * N + i0) * D;
    #pragma unroll
    for (int fm = 0; fm < 2; ++fm)
        #pragma unroll
        for (int fn = 0; fn < 4; ++fn)
            #pragma unroll
            for (int r = 0; r < 4; ++r) {
                int row = wr * 32 + fm * 16 + (lane >> 4) * 4 + r;
                int col = wc * 64 + fn * 16 + lr;
                ap[(long long)row * D + col] = f2bf(acc[fm][fn][r]);
            }
}

// ---------------------------------------------------------------------------
// Kernel 4: per row: psum = sum_s partial[s]; x = h + (1/psum) sum_s aggp[s];
//           z = x @ W^T + b; LN; ReLU; + h.  (aggp is bf16)
// ---------------------------------------------------------------------------
__global__ __launch_bounds__(128) void k_out(const float* __restrict__ h,
                                             const ushort* __restrict__ aggp,
                                             const float* __restrict__ partial,
                                             const float* __restrict__ Ww,
                                             const float* __restrict__ Wb,
                                             const float* __restrict__ ln_g,
                                             const float* __restrict__ ln_b,
                                             float* __restrict__ out) {
    __shared__ __align__(16) float x_s[D];
    __shared__ float red[4];
    constexpr long long BND = (long long)B * N * D;
    constexpr long long BN  = (long long)B * N;

    long long row = blockIdx.x;    // b*N + i
    int d = threadIdx.x;

    float hv = h[row * D + d];
    float a = 0.0f;
    #pragma unroll
    for (int s = 0; s < KS; ++s) {
        uint u = aggp[s * BND + row * D + d];
        a += __uint_as_float(u << 16);
    }
    float psum = 0.0f;
    #pragma unroll
    for (int s = 0; s < KS; ++s)
        psum += partial[s * BN + row];
    a *= (1.0f / psum);
    x_s[d] = hv + a;
    __syncthreads();

    const float4* wrow = reinterpret_cast<const float4*>(Ww + (long long)d * D);
    const float4* xv   = reinterpret_cast<const float4*>(x_s);
    float z = 0.0f;
    #pragma unroll
    for (int k = 0; k < D / 4; ++k) {
        float4 wv = wrow[k];
        float4 vv = xv[k];
        z += wv.x * vv.x + wv.y * vv.y + wv.z * vv.z + wv.w * vv.w;
    }
    z += Wb[d];

    float s = z;
    #pragma unroll
    for (int off = 32; off > 0; off >>= 1) s += __shfl_xor(s, off);
    if ((d & 63) == 0) red[d >> 6] = s;
    __syncthreads();
    float mu = (red[0] + red[1]) * (1.0f / (float)D);
    __syncthreads();

    float dev = z - mu;
    float s2 = dev * dev;
    #pragma unroll
    for (int off = 32; off > 0; off >>= 1) s2 += __shfl_xor(s2, off);
    if ((d & 63) == 0) red[d >> 6] = s2;
    __syncthreads();
    float var = (red[0] + red[1]) * (1.0f / (float)D);

    float y = dev * rsqrtf(var + LN_EPS) * ln_g[d] + ln_b[d];
    out[row * D + d] = fmaxf(y, 0.0f) + hv;
}

// ---------------------------------------------------------------------------
extern "C" void kernel_launch(void* const* d_in, const int* in_sizes, int n_in,
                              void* d_out, int out_size, void* d_ws, size_t ws_size,
                              hipStream_t stream) {
    const float* h    = (const float*)d_in[0];   // [B,N,D]
    const float* e    = (const float*)d_in[1];   // [B,N,N,De]
    const float* Ww   = (const float*)d_in[2];   // [D,D]
    const float* Wb   = (const float*)d_in[3];   // [D]
    const float* ln_g = (const float*)d_in[4];   // [D]
    const float* ln_b = (const float*)d_in[5];   // [D]

    float* out   = (float*)d_out;
    float* out_h = out;                                   // [B,N,D]
    float* out_e = out + (size_t)B * N * D;               // [B,N,N,De]

    ushort* w16  = (ushort*)d_ws;                         // [B,N,N] bf16   (33.5 MB)
    ushort* hT16 = w16 + (size_t)B * N * N;               // [B,D,N] bf16   (2.1 MB)
    ushort* aggp = hT16 + (size_t)B * D * N;              // [KS][B,N,D] bf16 (16.8 MB)
    float*  partial = (float*)(aggp + (size_t)KS * B * N * D);  // [KS][B*N] (256 KB)

    dim3 gh(N / 32, D / 32, B);
    k_hcast<<<gh, 256, 0, stream>>>(h, hT16);

    long long total_f4 = (long long)B * N * N * De / 4;   // 33.55M float4
    int eblocks = (int)(total_f4 / 1024);                 // 32768 blocks (16KB each)
    k_escore<<<eblocks, 256, 0, stream>>>(e, out_e, (uint*)w16);

    dim3 g2(N / 64, B, KS);
    k_agg<<<g2, 256, 0, stream>>>(w16, hT16, aggp, partial);
    k_out<<<B * N, 128, 0, stream>>>(h, aggp, partial, Ww, Wb, ln_g, ln_b, out_h);
}

// Round 18
// 284.448 us; speedup vs baseline: 1.1203x; 1.0054x over previous
//
#include <hip/hip_runtime.h>
#include <hip/hip_bf16.h>
#include <math.h>

// Problem constants (from reference setup_inputs)
constexpr int B  = 4;
constexpr int N  = 2048;
constexpr int D  = 128;
constexpr int De = 8;
constexpr int KS = 8;              // split-K factor for agg
constexpr float LN_EPS = 1e-5f;

typedef __bf16 bf16x8 __attribute__((ext_vector_type(8)));
typedef float  f32x4v __attribute__((ext_vector_type(4)));

__device__ inline ushort f2bf(float f) {
    uint u = __float_as_uint(f);
    return (ushort)((u + 0x7fffu + ((u >> 16) & 1u)) >> 16);   // RNE
}

// ---------------------------------------------------------------------------
// Kernel 1: hT16[b][d][n] = bf16(h[b][n][d])  -- transposed cast (2MB out).
// ---------------------------------------------------------------------------
__global__ __launch_bounds__(256) void k_hcast(const float* __restrict__ h,
                                               ushort* __restrict__ hT16) {
    __shared__ float tile[32][33];
    int b  = blockIdx.z;
    int n0 = blockIdx.x * 32, d0 = blockIdx.y * 32;
    int t  = threadIdx.x;
    int r = t >> 3, c = (t & 7) * 4;
    float4 v = *reinterpret_cast<const float4*>(h + ((long long)b * N + n0 + r) * D + d0 + c);
    tile[r][c] = v.x; tile[r][c + 1] = v.y; tile[r][c + 2] = v.z; tile[r][c + 3] = v.w;
    __syncthreads();
    ushort4 o;
    o.x = f2bf(tile[c + 0][r]);
    o.y = f2bf(tile[c + 1][r]);
    o.z = f2bf(tile[c + 2][r]);
    o.w = f2bf(tile[c + 3][r]);
    *reinterpret_cast<ushort4*>(hT16 + ((long long)b * D + d0 + r) * N + n0 + c) = o;
}

// ---------------------------------------------------------------------------
// Kernel 2: e-stream — ROUND-9 MEASURED-BEST FORM.
//   out_e = e (copy); w16 = bf16(exp(||e||))  [unnormalized numerator]
// Lane-contiguous (16B/lane, 1KB/wave/op); nt LOADS; cached stores; norm via
// shfl_xor(1); bf16 pack via shfl_xor(2); lanes t%4==0 write one uint.
// A/B history: this form 289.5 (r9) < ntstore 295.9 < ILP8+atomics 298.8 <
// item-per-lane 318.7. Max-subtraction skipped: ||e||<=~8.5 -> exp<=5e3.
// ---------------------------------------------------------------------------
__global__ __launch_bounds__(256) void k_escore(const float* __restrict__ e,
                                                float* __restrict__ out_e,
                                                uint* __restrict__ w32) {
    const f32x4v* src = reinterpret_cast<const f32x4v*>(e);
    f32x4v*       dst = reinterpret_cast<f32x4v*>(out_e);
    long long base = (long long)blockIdx.x * 1024;   // f4 units (16KB/block)
    int t = threadIdx.x;

    #pragma unroll
    for (int p = 0; p < 4; ++p) {
        long long i4 = base + p * 256 + t;
        f32x4v v = __builtin_nontemporal_load(&src[i4]);
        dst[i4] = v;
        float ss = v.x * v.x + v.y * v.y + v.z * v.z + v.w * v.w;
        ss += __shfl_xor(ss, 1);                     // full ||item||^2 on lane pair
        float val = __expf(sqrtf(ss));
        uint bf = f2bf(val);
        uint partner = (uint)__shfl_xor((int)bf, 2); // neighbor item's bf16
        if ((t & 3) == 0)
            w32[i4 >> 2] = bf | (partner << 16);
    }
}

// ---------------------------------------------------------------------------
// Kernel 3: MFMA split-K agg + fused row-sum (ones-vector MFMA).
//  aggp[z][b,i,:]  = sum_{j in slice} w_ij * h_j   (bf16 store, r17)
//  partial[z][b,i] = sum_{j in slice} w_ij          (fp32)
// r18 occupancy experiment: BK 64->32 (prefetch VGPR 24->12, LDS 27.6->15.4KB)
// + __launch_bounds__(256,4) -> 4 blocks/CU (16 waves/CU, was 12): +33% TLP
// against the global-load/barrier latency that r17 showed dominates k_agg.
// A = w16 [BM=64][32] bf16, B = hT16 [D=128][32] bf16, pitch 40 ushorts.
// 256 thr = 4 waves (2x2), wave-tile 32x64, 8 K-steps, register prefetch.
// grid (N/64, B, KS) = 1024 blocks.
// ---------------------------------------------------------------------------
__global__ __launch_bounds__(256, 4) void k_agg(const ushort* __restrict__ w16,
                                                const ushort* __restrict__ hT16,
                                                ushort* __restrict__ aggp,
                                                float* __restrict__ partial) {
    constexpr int BM = 64;
    constexpr int BK = 32;
    constexpr int KC = N / KS;            // 256
    __shared__ ushort A_s[BM][40];        // w rows (80B pitch)
    __shared__ ushort B_s[D][40];         // h cols (hT rows)

    int b  = blockIdx.y;
    int i0 = blockIdx.x * BM;
    int kbase = blockIdx.z * KC;
    int t  = threadIdx.x;
    int wid = t >> 6, lane = t & 63;
    int wr = wid >> 1, wc = wid & 1;      // wave tile: rows wr*32.., cols wc*64..
    int lr = lane & 15, lk = (lane >> 4) * 8;

    const ushort* wb = w16 + ((long long)b * N + i0) * N + kbase;
    const ushort* hb = hT16 + (long long)b * D * N + kbase;

    f32x4v acc[2][4] = {};
    f32x4v acc_sum[2] = {};               // ones-MFMA row-sum accumulators

    ushort one_bits = 0x3F80;             // 1.0 bf16
    __bf16 one_bf = *reinterpret_cast<__bf16*>(&one_bits);
    bf16x8 ones = {one_bf, one_bf, one_bf, one_bf, one_bf, one_bf, one_bf, one_bf};

    int ar = t >> 2, ac = (t & 3) * 8;    // A stage: 64 rows x 4 quads
    int q1 = t + 256;                     // B stage: 512 quads, 2/thread

    // prologue: load tile 0
    uint4 av  = *reinterpret_cast<const uint4*>(wb + (long long)ar * N + ac);
    uint4 bv0 = *reinterpret_cast<const uint4*>(hb + (long long)(t >> 2) * N + (t & 3) * 8);
    uint4 bv1 = *reinterpret_cast<const uint4*>(hb + (long long)(q1 >> 2) * N + (q1 & 3) * 8);

    for (int k0 = 0; k0 < KC; k0 += BK) {
        __syncthreads();   // previous iteration's frag reads done
        *reinterpret_cast<uint4*>(&A_s[ar][ac]) = av;
        *reinterpret_cast<uint4*>(&B_s[t >> 2][(t & 3) * 8]) = bv0;
        *reinterpret_cast<uint4*>(&B_s[q1 >> 2][(q1 & 3) * 8]) = bv1;
        __syncthreads();   // tile ready

        int kn = k0 + BK;
        if (kn < KC) {     // prefetch next tile; latency hides under MFMAs
            av  = *reinterpret_cast<const uint4*>(wb + (long long)ar * N + kn + ac);
            bv0 = *reinterpret_cast<const uint4*>(hb + (long long)(t >> 2) * N + kn + (t & 3) * 8);
            bv1 = *reinterpret_cast<const uint4*>(hb + (long long)(q1 >> 2) * N + kn + (q1 & 3) * 8);
        }

        bf16x8 af[2], bfr[4];
        #pragma unroll
        for (int fm = 0; fm < 2; ++fm)
            af[fm] = *reinterpret_cast<const bf16x8*>(&A_s[wr * 32 + fm * 16 + lr][lk]);
        #pragma unroll
        for (int fn = 0; fn < 4; ++fn)
            bfr[fn] = *reinterpret_cast<const bf16x8*>(&B_s[wc * 64 + fn * 16 + lr][lk]);
        #pragma unroll
        for (int fm = 0; fm < 2; ++fm) {
            #pragma unroll
            for (int fn = 0; fn < 4; ++fn)
                acc[fm][fn] = __builtin_amdgcn_mfma_f32_16x16x32_bf16(
                    af[fm], bfr[fn], acc[fm][fn], 0, 0, 0);
            acc_sum[fm] = __builtin_amdgcn_mfma_f32_16x16x32_bf16(
                af[fm], ones, acc_sum[fm], 0, 0, 0);
        }
    }

    // row-sum partials: col 0 of the sum fragment; wc==0 waves, lr==0 lanes.
    if (wc == 0 && lr == 0) {
        float* pp = partial + (long long)blockIdx.z * (B * N) + (long long)b * N + i0;
        #pragma unroll
        for (int fm = 0; fm < 2; ++fm)
            #pragma unroll
            for (int r = 0; r < 4; ++r)
                pp[wr * 32 + fm * 16 + (lane >> 4) * 4 + r] = acc_sum[fm][r];
    }

    // D frag: row m = (lane>>4)*4 + r, col n = lane&15  [m89-verified layout]
    ushort* ap = aggp + (long long)blockIdx.z * B * N * D + ((long long)b * N + i0) * D;
    #pragma unroll
    for (int fm = 0; fm < 2; ++fm)
        #pragma unroll
        for (int fn = 0; fn < 4; ++fn)
            #pragma unroll
            for (int r = 0; r < 4; ++r) {
                int row = wr * 32 + fm * 16 + (lane >> 4) * 4 + r;
                int col = wc * 64 + fn * 16 + lr;
                ap[(long long)row * D + col] = f2bf(acc[fm][fn][r]);
            }
}

// ---------------------------------------------------------------------------
// Kernel 4: per row: psum = sum_s partial[s]; x = h + (1/psum) sum_s aggp[s];
//           z = x @ W^T + b; LN; ReLU; + h.  (aggp is bf16)
// ---------------------------------------------------------------------------
__global__ __launch_bounds__(128) void k_out(const float* __restrict__ h,
                                             const ushort* __restrict__ aggp,
                                             const float* __restrict__ partial,
                                             const float* __restrict__ Ww,
                                             const float* __restrict__ Wb,
                                             const float* __restrict__ ln_g,
                                             const float* __restrict__ ln_b,
                                             float* __restrict__ out) {
    __shared__ __align__(16) float x_s[D];
    __shared__ float red[4];
    constexpr long long BND = (long long)B * N * D;
    constexpr long long BN  = (long long)B * N;

    long long row = blockIdx.x;    // b*N + i
    int d = threadIdx.x;

    float hv = h[row * D + d];
    float a = 0.0f;
    #pragma unroll
    for (int s = 0; s < KS; ++s) {
        uint u = aggp[s * BND + row * D + d];
        a += __uint_as_float(u << 16);
    }
    float psum = 0.0f;
    #pragma unroll
    for (int s = 0; s < KS; ++s)
        psum += partial[s * BN + row];
    a *= (1.0f / psum);
    x_s[d] = hv + a;
    __syncthreads();

    const float4* wrow = reinterpret_cast<const float4*>(Ww + (long long)d * D);
    const float4* xv   = reinterpret_cast<const float4*>(x_s);
    float z = 0.0f;
    #pragma unroll
    for (int k = 0; k < D / 4; ++k) {
        float4 wv = wrow[k];
        float4 vv = xv[k];
        z += wv.x * vv.x + wv.y * vv.y + wv.z * vv.z + wv.w * vv.w;
    }
    z += Wb[d];

    float s = z;
    #pragma unroll
    for (int off = 32; off > 0; off >>= 1) s += __shfl_xor(s, off);
    if ((d & 63) == 0) red[d >> 6] = s;
    __syncthreads();
    float mu = (red[0] + red[1]) * (1.0f / (float)D);
    __syncthreads();

    float dev = z - mu;
    float s2 = dev * dev;
    #pragma unroll
    for (int off = 32; off > 0; off >>= 1) s2 += __shfl_xor(s2, off);
    if ((d & 63) == 0) red[d >> 6] = s2;
    __syncthreads();
    float var = (red[0] + red[1]) * (1.0f / (float)D);

    float y = dev * rsqrtf(var + LN_EPS) * ln_g[d] + ln_b[d];
    out[row * D + d] = fmaxf(y, 0.0f) + hv;
}

// ---------------------------------------------------------------------------
extern "C" void kernel_launch(void* const* d_in, const int* in_sizes, int n_in,
                              void* d_out, int out_size, void* d_ws, size_t ws_size,
                              hipStream_t stream) {
    const float* h    = (const float*)d_in[0];   // [B,N,D]
    const float* e    = (const float*)d_in[1];   // [B,N,N,De]
    const float* Ww   = (const float*)d_in[2];   // [D,D]
    const float* Wb   = (const float*)d_in[3];   // [D]
    const float* ln_g = (const float*)d_in[4];   // [D]
    const float* ln_b = (const float*)d_in[5];   // [D]

    float* out   = (float*)d_out;
    float* out_h = out;                                   // [B,N,D]
    float* out_e = out + (size_t)B * N * D;               // [B,N,N,De]

    ushort* w16  = (ushort*)d_ws;                         // [B,N,N] bf16   (33.5 MB)
    ushort* hT16 = w16 + (size_t)B * N * N;               // [B,D,N] bf16   (2.1 MB)
    ushort* aggp = hT16 + (size_t)B * D * N;              // [KS][B,N,D] bf16 (16.8 MB)
    float*  partial = (float*)(aggp + (size_t)KS * B * N * D);  // [KS][B*N] (256 KB)

    dim3 gh(N / 32, D / 32, B);
    k_hcast<<<gh, 256, 0, stream>>>(h, hT16);

    long long total_f4 = (long long)B * N * N * De / 4;   // 33.55M float4
    int eblocks = (int)(total_f4 / 1024);                 // 32768 blocks (16KB each)
    k_escore<<<eblocks, 256, 0, stream>>>(e, out_e, (uint*)w16);

    dim3 g2(N / 64, B, KS);
    k_agg<<<g2, 256, 0, stream>>>(w16, hT16, aggp, partial);
    k_out<<<B * N, 128, 0, stream>>>(h, aggp, partial, Ww, Wb, ln_g, ln_b, out_h);
}